// Round 1
// baseline (1230.077 us; speedup 1.0000x reference)
//
#include <hip/hip_runtime.h>
#include <hip/hip_bf16.h>
#include <cstdint>

#define B_   8
#define S_   2048
#define DIN  512
#define DH   512

typedef __attribute__((ext_vector_type(8))) short  short8;
typedef __attribute__((ext_vector_type(4))) float  float4_;

__device__ inline unsigned short f2bf(float f) {
    union { float f; unsigned u; } v; v.f = f;
    unsigned u = v.u;
    u += 0x7fffu + ((u >> 16) & 1u);   // RNE
    return (unsigned short)(u >> 16);
}

// ---------------------------------------------------------------------------
// Stage 1: fused QKV projection.  y = x @ W^T + b  for W in {Wq,Wk,Wv}.
// Writes bf16: Q (scaled by 1/sqrt(DH)) [m][d], K [m][d], V transposed [b][h][s].
// Grid: (M/64, 24) ; block 256 (4 waves), wave computes 16 rows x 64 cols.
// ---------------------------------------------------------------------------
__global__ __launch_bounds__(256) void qkv_gemm(
    const float* __restrict__ x,
    const float* __restrict__ Wq, const float* __restrict__ bq,
    const float* __restrict__ Wk, const float* __restrict__ bk,
    const float* __restrict__ Wv, const float* __restrict__ bv,
    unsigned short* __restrict__ qws, unsigned short* __restrict__ kws,
    unsigned short* __restrict__ vtws)
{
    const int bx   = blockIdx.x;        // 256 row-blocks of 64
    const int by   = blockIdx.y;        // 24 = 3 mats * 8 col-blocks
    const int tid  = threadIdx.x;
    const int w    = tid >> 6;
    const int lane = tid & 63;
    const int l15  = lane & 15;
    const int quad = lane >> 4;

    const int mat  = by >> 3;           // 0=Q 1=K 2=V
    const int col0 = (by & 7) * 64;
    const float* W    = (mat == 0) ? Wq : (mat == 1) ? Wk : Wv;
    const float* bias = (mat == 0) ? bq : (mat == 1) ? bk : bv;

    const int rowA = bx * 64 + w * 16 + l15;   // A-frag row (m = lane&15)

    float4_ zero = {0.f, 0.f, 0.f, 0.f};
    float4_ acc[4];
    #pragma unroll
    for (int i = 0; i < 4; i++) acc[i] = zero;

    for (int kk = 0; kk < DIN; kk += 32) {
        // A frag: x[rowA][kk + quad*8 .. +8]  (8 fp32 -> bf16)
        const float4_* ap = (const float4_*)(x + (size_t)rowA * DIN + kk + quad * 8);
        float4_ a0 = ap[0], a1 = ap[1];
        short8 afr;
        #pragma unroll
        for (int j = 0; j < 4; j++) { afr[j] = (short)f2bf(a0[j]); afr[4 + j] = (short)f2bf(a1[j]); }
        #pragma unroll
        for (int ct = 0; ct < 4; ct++) {
            int n = col0 + ct * 16 + l15;       // output col = W row
            const float4_* bp = (const float4_*)(W + (size_t)n * DIN + kk + quad * 8);
            float4_ b0 = bp[0], b1 = bp[1];
            short8 bfr;
            #pragma unroll
            for (int j = 0; j < 4; j++) { bfr[j] = (short)f2bf(b0[j]); bfr[4 + j] = (short)f2bf(b1[j]); }
            acc[ct] = __builtin_amdgcn_mfma_f32_16x16x32_bf16(afr, bfr, acc[ct], 0, 0, 0);
        }
    }

    const float scale = 0.044194173824159216f;  // 1/sqrt(512)
    #pragma unroll
    for (int ct = 0; ct < 4; ct++) {
        int n = col0 + ct * 16 + l15;
        float bv_ = bias[n];
        #pragma unroll
        for (int r = 0; r < 4; r++) {
            int m = bx * 64 + w * 16 + quad * 4 + r;   // C row = quad*4+reg
            float y = acc[ct][r] + bv_;
            if (mat == 0) {
                qws[(size_t)m * DH + n] = f2bf(y * scale);
            } else if (mat == 1) {
                kws[(size_t)m * DH + n] = f2bf(y);
            } else {
                int b = m >> 11, s = m & 2047;
                vtws[((size_t)(b * DH + n) << 11) + s] = f2bf(y);
            }
        }
    }
}

// ---------------------------------------------------------------------------
// Stage 2: flash attention.  Grid: 256 blocks (8 batches x 32 q-tiles of 64),
// block 256 = 4 waves, each wave owns 16 q rows, full DH=512 output in regs.
// ---------------------------------------------------------------------------
__global__ __launch_bounds__(256, 1) void attn(
    const unsigned short* __restrict__ qws,
    const unsigned short* __restrict__ kws,
    const unsigned short* __restrict__ vtws,
    float* __restrict__ out)
{
    __shared__ unsigned short lds_p[4][16][32];   // per-wave P transpose buffer

    const int bid  = blockIdx.x;       // 256
    const int b    = bid >> 5;
    const int tid  = threadIdx.x;
    const int w    = tid >> 6;
    const int lane = tid & 63;
    const int l15  = lane & 15;
    const int quad = lane >> 4;

    const int grow = bid * 64 + w * 16;          // wave's base global q row

    // Preload Q fragments (16 k-steps of 32): 64 VGPRs
    short8 qf[16];
    const short8* qp = (const short8*)(qws + (size_t)(grow + l15) * DH);
    #pragma unroll
    for (int ksi = 0; ksi < 16; ksi++) qf[ksi] = qp[ksi * 4 + quad];

    float4_ zero = {0.f, 0.f, 0.f, 0.f};
    float4_ o[32];
    #pragma unroll
    for (int i = 0; i < 32; i++) o[i] = zero;
    float m_[4], l_[4];
    #pragma unroll
    for (int r = 0; r < 4; r++) { m_[r] = -INFINITY; l_[r] = 0.f; }

    const unsigned short* kbase = kws + (((size_t)b) << 11) * DH;
    const unsigned short* vbase = vtws + (((size_t)b * DH) << 11);

    for (int kt = 0; kt < S_; kt += 32) {
        // ---- scores: S = Qs * K^T  (16 q-rows x 32 keys) ----
        float4_ sc[2];
        sc[0] = zero; sc[1] = zero;
        #pragma unroll
        for (int ksi = 0; ksi < 16; ksi++) {
            #pragma unroll
            for (int t = 0; t < 2; t++) {
                const short8* kp = (const short8*)(kbase + (size_t)(kt + t * 16 + l15) * DH);
                short8 kf = kp[ksi * 4 + quad];
                sc[t] = __builtin_amdgcn_mfma_f32_16x16x32_bf16(qf[ksi], kf, sc[t], 0, 0, 0);
            }
        }
        // ---- online softmax (rows live at quad*4+reg, keys at lane&15) ----
        float alpha[4], p0[4], p1[4];
        #pragma unroll
        for (int r = 0; r < 4; r++) {
            float v = fmaxf(sc[0][r], sc[1][r]);
            v = fmaxf(v, __shfl_xor(v, 1));
            v = fmaxf(v, __shfl_xor(v, 2));
            v = fmaxf(v, __shfl_xor(v, 4));
            v = fmaxf(v, __shfl_xor(v, 8));
            float mn = fmaxf(m_[r], v);
            alpha[r] = __expf(m_[r] - mn);
            m_[r] = mn;
            p0[r] = __expf(sc[0][r] - mn);
            p1[r] = __expf(sc[1][r] - mn);
            float s = p0[r] + p1[r];
            s += __shfl_xor(s, 1);
            s += __shfl_xor(s, 2);
            s += __shfl_xor(s, 4);
            s += __shfl_xor(s, 8);
            l_[r] = l_[r] * alpha[r] + s;
        }
        // rescale O by alpha (per C-row mapping, same as acc layout)
        #pragma unroll
        for (int ct = 0; ct < 32; ct++) {
            #pragma unroll
            for (int r = 0; r < 4; r++) o[ct][r] *= alpha[r];
        }
        // ---- P: C-layout -> A-layout via per-wave LDS ----
        #pragma unroll
        for (int r = 0; r < 4; r++) {
            lds_p[w][quad * 4 + r][l15]      = f2bf(p0[r]);
            lds_p[w][quad * 4 + r][16 + l15] = f2bf(p1[r]);
        }
        __syncthreads();
        short8 pf = *(const short8*)&lds_p[w][l15][quad * 8];
        // ---- O += P * V  (k = 32 keys in one MFMA k-step) ----
        #pragma unroll
        for (int ct = 0; ct < 32; ct++) {
            const short8* vp = (const short8*)(vbase + (((size_t)(ct * 16 + l15)) << 11) + kt);
            short8 vf = vp[quad];
            o[ct] = __builtin_amdgcn_mfma_f32_16x16x32_bf16(pf, vf, o[ct], 0, 0, 0);
        }
        __syncthreads();
    }

    // epilogue: normalize and store fp32
    float rl[4];
    #pragma unroll
    for (int r = 0; r < 4; r++) rl[r] = 1.f / l_[r];
    #pragma unroll
    for (int ct = 0; ct < 32; ct++) {
        #pragma unroll
        for (int r = 0; r < 4; r++) {
            out[(size_t)(grow + quad * 4 + r) * DH + ct * 16 + l15] = o[ct][r] * rl[r];
        }
    }
}

extern "C" void kernel_launch(void* const* d_in, const int* in_sizes, int n_in,
                              void* d_out, int out_size, void* d_ws, size_t ws_size,
                              hipStream_t stream) {
    const float* x  = (const float*)d_in[0];
    const float* Wq = (const float*)d_in[1];
    const float* bq = (const float*)d_in[2];
    const float* Wk = (const float*)d_in[3];
    const float* bk = (const float*)d_in[4];
    const float* Wv = (const float*)d_in[5];
    const float* bv = (const float*)d_in[6];
    float* out = (float*)d_out;

    unsigned short* qws = (unsigned short*)d_ws;                 // [16384][512] bf16 (scaled)
    unsigned short* kws = qws + (size_t)B_ * S_ * DH;            // [16384][512] bf16
    unsigned short* vt  = kws + (size_t)B_ * S_ * DH;            // [8][512][2048] bf16

    dim3 g1(256, 24);
    qkv_gemm<<<g1, dim3(256), 0, stream>>>(x, Wq, bq, Wk, bk, Wv, bv, qws, kws, vt);
    attn<<<dim3(256), dim3(256), 0, stream>>>(qws, kws, vt, out);
}

// Round 2
// 491.766 us; speedup vs baseline: 2.5013x; 2.5013x over previous
//
#include <hip/hip_runtime.h>
#include <hip/hip_bf16.h>
#include <cstdint>

#define B_   8
#define S_   2048
#define DIN  512
#define DH   512

typedef __attribute__((ext_vector_type(8))) short  short8;
typedef __attribute__((ext_vector_type(4))) short  short4_;
typedef __attribute__((ext_vector_type(4))) float  float4_;

__device__ inline unsigned short f2bf(float f) {
    union { float f; unsigned u; } v; v.f = f;
    unsigned u = v.u;
    u += 0x7fffu + ((u >> 16) & 1u);   // RNE
    return (unsigned short)(u >> 16);
}

// async global->LDS, 16B per lane; LDS dest = wave-uniform base + lane*16
__device__ inline void gload_lds16(const void* g, void* l) {
    __builtin_amdgcn_global_load_lds(
        (const __attribute__((address_space(1))) void*)g,
        (__attribute__((address_space(3))) void*)l, 16, 0, 0);
}

// ---------------------------------------------------------------------------
// Kernel 0: convert x (fp32) and Wq/Wk/Wv (fp32) to bf16 scratch.
// xb/wb live inside d_out (attn fully overwrites d_out at the end).
// ---------------------------------------------------------------------------
__global__ __launch_bounds__(256) void conv_bf16(
    const float* __restrict__ x,
    const float* __restrict__ Wq, const float* __restrict__ Wk, const float* __restrict__ Wv,
    unsigned short* __restrict__ xb, unsigned short* __restrict__ wb)
{
    const int NX4 = (B_ * S_ * DIN) / 4;   // 2,097,152 float4 groups
    const int NW4 = (DH * DIN) / 4;        // 65,536
    const int total = NX4 + 3 * NW4;
    for (int i = blockIdx.x * blockDim.x + threadIdx.x; i < total;
         i += gridDim.x * blockDim.x) {
        const float4_* src; unsigned short* dst; int j;
        if (i < NX4)            { src = (const float4_*)x;  dst = xb;              j = i; }
        else if (i < NX4 + NW4) { src = (const float4_*)Wq; dst = wb;              j = i - NX4; }
        else if (i < NX4 + 2*NW4){ src = (const float4_*)Wk; dst = wb + DH*DIN;     j = i - NX4 - NW4; }
        else                    { src = (const float4_*)Wv; dst = wb + 2*DH*DIN;   j = i - NX4 - 2*NW4; }
        float4_ v = src[j];
        short4_ o;
        o[0] = (short)f2bf(v[0]); o[1] = (short)f2bf(v[1]);
        o[2] = (short)f2bf(v[2]); o[3] = (short)f2bf(v[3]);
        ((short4_*)dst)[j] = o;
    }
}

// ---------------------------------------------------------------------------
// Kernel 1: QKV projection, m97-style LDS-staged bf16 MFMA GEMM.
// Grid (128 row-tiles of 128, 12 col-tiles: 3 mats x 4x128 cols), block 256.
// Wave computes 64x64 (4x4 tiles of 16x16x32). Epilogue: +bias, Q scaled,
// V stored transposed [b][h][s].
// ---------------------------------------------------------------------------
__global__ __launch_bounds__(256) void qkv_gemm(
    const unsigned short* __restrict__ xb,   // [16384][512] bf16
    const unsigned short* __restrict__ wb,   // [3][512][512] bf16
    const float* __restrict__ bq, const float* __restrict__ bk, const float* __restrict__ bv,
    unsigned short* __restrict__ qws, unsigned short* __restrict__ kws,
    unsigned short* __restrict__ vtws)
{
    __shared__ unsigned short Ab[128 * 32];  // [128 rows][32 k] bf16, 8 KB
    __shared__ unsigned short Bb[128 * 32];

    const int tm   = blockIdx.x;             // 0..127
    const int tc   = blockIdx.y;             // 0..11
    const int mat  = tc >> 2;                // 0=Q 1=K 2=V
    const int nb   = (tc & 3) * 128;         // col base within mat
    const int tid  = threadIdx.x;
    const int w    = tid >> 6;
    const int lane = tid & 63;
    const int l15  = lane & 15;
    const int quad = lane >> 4;
    const int wm   = (w & 1) * 64;
    const int wn   = (w >> 1) * 64;
    const int m0   = tm * 128;

    const unsigned short* wmat = wb + (size_t)mat * DH * DIN;

    float4_ zero = {0.f, 0.f, 0.f, 0.f};
    float4_ acc[4][4];
    #pragma unroll
    for (int i = 0; i < 4; i++)
        #pragma unroll
        for (int j = 0; j < 4; j++) acc[i][j] = zero;

    const int lr = lane >> 2;        // staging: row within 16-row chunk
    const int lb = (lane & 3) * 16;  // staging: byte offset within 64B row

    for (int kk = 0; kk < DIN; kk += 32) {
        #pragma unroll
        for (int c = 0; c < 2; c++) {
            int r = w * 32 + c * 16;   // tile row base for this instr
            const unsigned char* gA = (const unsigned char*)(xb + (size_t)(m0 + r) * DIN + kk);
            gload_lds16(gA + (size_t)lr * (DIN * 2) + lb, (void*)(Ab + r * 32));
            const unsigned char* gB = (const unsigned char*)(wmat + (size_t)(nb + r) * DIN + kk);
            gload_lds16(gB + (size_t)lr * (DIN * 2) + lb, (void*)(Bb + r * 32));
        }
        __syncthreads();
        short8 af[4], bf[4];
        #pragma unroll
        for (int mt = 0; mt < 4; mt++)
            af[mt] = *(const short8*)(Ab + (wm + mt * 16 + l15) * 32 + quad * 8);
        #pragma unroll
        for (int nt = 0; nt < 4; nt++)
            bf[nt] = *(const short8*)(Bb + (wn + nt * 16 + l15) * 32 + quad * 8);
        #pragma unroll
        for (int mt = 0; mt < 4; mt++)
            #pragma unroll
            for (int nt = 0; nt < 4; nt++)
                acc[mt][nt] = __builtin_amdgcn_mfma_f32_16x16x32_bf16(af[mt], bf[nt], acc[mt][nt], 0, 0, 0);
        __syncthreads();
    }

    const float* bias  = (mat == 0) ? bq : (mat == 1) ? bk : bv;
    const float  scale = (mat == 0) ? 0.044194173824159216f : 1.0f;  // 1/sqrt(512) on Q
    #pragma unroll
    for (int nt = 0; nt < 4; nt++) {
        int n = nb + wn + nt * 16 + l15;       // col within mat
        float bv_ = bias[n];
        #pragma unroll
        for (int mt = 0; mt < 4; mt++) {
            #pragma unroll
            for (int r = 0; r < 4; r++) {
                int m = m0 + wm + mt * 16 + quad * 4 + r;
                float y = (acc[mt][nt][r] + bv_) * scale;
                if (mat == 0) {
                    qws[(size_t)m * DH + n] = f2bf(y);
                } else if (mat == 1) {
                    kws[(size_t)m * DH + n] = f2bf(y);
                } else {
                    int bi = m >> 11, s = m & 2047;
                    vtws[((size_t)(bi * DH + n) << 11) + s] = f2bf(y);
                }
            }
        }
    }
}

// ---------------------------------------------------------------------------
// Kernel 2: flash attention. 256 blocks (batch = bid&7 -> XCD-local K/V),
// block 256 = 4 waves, wave owns 16 q-rows, O (16x512) in regs.
// K-tile (32 keys x 512) staged in LDS (padded rows, 1040B); V direct-global
// with 2-deep prefetch; P transposed through per-wave LDS (no barrier).
// ---------------------------------------------------------------------------
__global__ __launch_bounds__(256, 1) void attn(
    const unsigned short* __restrict__ qws,
    const unsigned short* __restrict__ kws,
    const unsigned short* __restrict__ vtws,
    float* __restrict__ out)
{
    __shared__ unsigned char  kb[32 * 1040];        // 33.3 KB K tile
    __shared__ unsigned short lds_p[4][16][32];     // 4 KB per-wave P transpose

    const int bid  = blockIdx.x;        // 256
    const int b    = bid & 7;           // batch == XCD (round-robin dispatch)
    const int qt   = bid >> 3;          // 0..31 q-tile within batch
    const int tid  = threadIdx.x;
    const int w    = tid >> 6;
    const int lane = tid & 63;
    const int l15  = lane & 15;
    const int quad = lane >> 4;

    const int grow = b * S_ + qt * 64 + w * 16;   // wave's base global q row

    // Q fragments resident: 16 k-steps of 32 -> 64 VGPRs
    short8 qf[16];
    const short8* qp = (const short8*)(qws + (size_t)(grow + l15) * DH);
    #pragma unroll
    for (int ksi = 0; ksi < 16; ksi++) qf[ksi] = qp[ksi * 4 + quad];

    float4_ zero = {0.f, 0.f, 0.f, 0.f};
    float4_ o[32];
    #pragma unroll
    for (int i = 0; i < 32; i++) o[i] = zero;
    float m_[4], l_[4];
    #pragma unroll
    for (int r = 0; r < 4; r++) { m_[r] = -INFINITY; l_[r] = 0.f; }

    const unsigned short* kbase = kws + (((size_t)b) << 11) * DH;
    const unsigned short* vbase = vtws + (((size_t)b * DH) << 11);

    for (int kt = 0; kt < S_; kt += 32) {
        // ---- stage K tile: 8 rows per wave, 1 row (1 KB) per instr ----
        #pragma unroll
        for (int c = 0; c < 8; c++) {
            int row = w * 8 + c;
            const unsigned char* g = (const unsigned char*)(kbase + (size_t)(kt + row) * DH);
            gload_lds16(g + lane * 16, kb + row * 1040);
        }
        __syncthreads();   // K tile visible

        // ---- scores: S = Q * K^T (16 q x 32 keys) ----
        float4_ sc[2];
        sc[0] = zero; sc[1] = zero;
        #pragma unroll
        for (int ksi = 0; ksi < 16; ksi++) {
            #pragma unroll
            for (int t = 0; t < 2; t++) {
                short8 kf = *(const short8*)(kb + (t * 16 + l15) * 1040 + ksi * 64 + quad * 16);
                sc[t] = __builtin_amdgcn_mfma_f32_16x16x32_bf16(qf[ksi], kf, sc[t], 0, 0, 0);
            }
        }

        // ---- online softmax (q rows at quad*4+r, keys at lane&15) ----
        float alpha[4], p0[4], p1[4];
        #pragma unroll
        for (int r = 0; r < 4; r++) {
            float v = fmaxf(sc[0][r], sc[1][r]);
            v = fmaxf(v, __shfl_xor(v, 1));
            v = fmaxf(v, __shfl_xor(v, 2));
            v = fmaxf(v, __shfl_xor(v, 4));
            v = fmaxf(v, __shfl_xor(v, 8));
            float mn = fmaxf(m_[r], v);
            alpha[r] = __expf(m_[r] - mn);
            m_[r] = mn;
            p0[r] = __expf(sc[0][r] - mn);
            p1[r] = __expf(sc[1][r] - mn);
            float s = p0[r] + p1[r];
            s += __shfl_xor(s, 1);
            s += __shfl_xor(s, 2);
            s += __shfl_xor(s, 4);
            s += __shfl_xor(s, 8);
            l_[r] = l_[r] * alpha[r] + s;
        }

        // ---- P: C-layout -> A-layout via per-wave LDS (no barrier needed) ----
        #pragma unroll
        for (int r = 0; r < 4; r++) {
            lds_p[w][quad * 4 + r][l15]      = f2bf(p0[r]);
            lds_p[w][quad * 4 + r][16 + l15] = f2bf(p1[r]);
        }
        short8 pf = *(const short8*)&lds_p[w][l15][quad * 8];

        // ---- rescale O only when a new max appeared (wave-uniform skip) ----
        float amin = fminf(fminf(alpha[0], alpha[1]), fminf(alpha[2], alpha[3]));
        if (__any(amin < 1.0f)) {
            #pragma unroll
            for (int ct = 0; ct < 32; ct++) {
                #pragma unroll
                for (int r = 0; r < 4; r++) o[ct][r] *= alpha[r];
            }
        }

        // ---- O += P * V : 8 chunks of 4, 2-deep V prefetch ----
        short8 vf[2][4];
        #pragma unroll
        for (int j = 0; j < 4; j++) {
            const unsigned short* vp = vbase + ((size_t)(j * 16 + l15) << 11) + kt;
            vf[0][j] = *(const short8*)(vp + quad * 8);
        }
        #pragma unroll
        for (int c = 0; c < 8; c++) {
            if (c < 7) {
                #pragma unroll
                for (int j = 0; j < 4; j++) {
                    const unsigned short* vp = vbase + ((size_t)((c + 1) * 64 + j * 16 + l15) << 11) + kt;
                    vf[(c + 1) & 1][j] = *(const short8*)(vp + quad * 8);
                }
            }
            #pragma unroll
            for (int j = 0; j < 4; j++)
                o[c * 4 + j] = __builtin_amdgcn_mfma_f32_16x16x32_bf16(pf, vf[c & 1][j], o[c * 4 + j], 0, 0, 0);
        }
        __syncthreads();   // all waves done with kb before next staging
    }

    float rl[4];
    #pragma unroll
    for (int r = 0; r < 4; r++) rl[r] = 1.f / l_[r];
    #pragma unroll
    for (int ct = 0; ct < 32; ct++) {
        #pragma unroll
        for (int r = 0; r < 4; r++) {
            out[(size_t)(grow + quad * 4 + r) * DH + ct * 16 + l15] = o[ct][r] * rl[r];
        }
    }
}

extern "C" void kernel_launch(void* const* d_in, const int* in_sizes, int n_in,
                              void* d_out, int out_size, void* d_ws, size_t ws_size,
                              hipStream_t stream) {
    const float* x  = (const float*)d_in[0];
    const float* Wq = (const float*)d_in[1];
    const float* bq = (const float*)d_in[2];
    const float* Wk = (const float*)d_in[3];
    const float* bk = (const float*)d_in[4];
    const float* Wv = (const float*)d_in[5];
    const float* bv = (const float*)d_in[6];
    float* out = (float*)d_out;

    // workspace: proven-safe 50.3 MB layout (same as R1)
    unsigned short* qws = (unsigned short*)d_ws;                 // [16384][512] bf16 (pre-scaled)
    unsigned short* kws = qws + (size_t)B_ * S_ * DH;            // [16384][512] bf16
    unsigned short* vt  = kws + (size_t)B_ * S_ * DH;            // [8][512][2048] bf16

    // bf16 staging scratch lives in d_out (fully overwritten by attn at the end)
    unsigned short* xb = (unsigned short*)d_out;                 // [16384][512] bf16 (16.8 MB)
    unsigned short* wb = xb + (size_t)B_ * S_ * DIN;             // [3][512][512] bf16 (1.6 MB)

    conv_bf16<<<dim3(2048), dim3(256), 0, stream>>>(x, Wq, Wk, Wv, xb, wb);
    qkv_gemm<<<dim3(128, 12), dim3(256), 0, stream>>>(xb, wb, bq, bk, bv, qws, kws, vt);
    attn<<<dim3(256), dim3(256), 0, stream>>>(qws, kws, vt, out);
}

// Round 3
// 354.866 us; speedup vs baseline: 3.4663x; 1.3858x over previous
//
#include <hip/hip_runtime.h>
#include <hip/hip_bf16.h>
#include <cstdint>

#define B_   8
#define S_   2048
#define DIN  512
#define DH   512

typedef __attribute__((ext_vector_type(8))) short  short8;
typedef __attribute__((ext_vector_type(4))) short  short4_;
typedef __attribute__((ext_vector_type(4))) float  float4_;

__device__ inline unsigned short f2bf(float f) {
    union { float f; unsigned u; } v; v.f = f;
    unsigned u = v.u;
    u += 0x7fffu + ((u >> 16) & 1u);   // RNE
    return (unsigned short)(u >> 16);
}

// async global->LDS, 16B per lane; LDS dest = wave-uniform base + lane*16
__device__ inline void gload_lds16(const void* g, void* l) {
    __builtin_amdgcn_global_load_lds(
        (const __attribute__((address_space(1))) void*)g,
        (__attribute__((address_space(3))) void*)l, 16, 0, 0);
}

// ---------------------------------------------------------------------------
// Kernel 0: convert x and Wq/Wk/Wv fp32 -> bf16 scratch (in d_out, overwritten
// later by attn's final store).
// ---------------------------------------------------------------------------
__global__ __launch_bounds__(256) void conv_bf16(
    const float* __restrict__ x,
    const float* __restrict__ Wq, const float* __restrict__ Wk, const float* __restrict__ Wv,
    unsigned short* __restrict__ xb, unsigned short* __restrict__ wb)
{
    const int NX4 = (B_ * S_ * DIN) / 4;
    const int NW4 = (DH * DIN) / 4;
    const int total = NX4 + 3 * NW4;
    for (int i = blockIdx.x * blockDim.x + threadIdx.x; i < total;
         i += gridDim.x * blockDim.x) {
        const float4_* src; unsigned short* dst; int j;
        if (i < NX4)             { src = (const float4_*)x;  dst = xb;            j = i; }
        else if (i < NX4 + NW4)  { src = (const float4_*)Wq; dst = wb;            j = i - NX4; }
        else if (i < NX4 + 2*NW4){ src = (const float4_*)Wk; dst = wb + DH*DIN;   j = i - NX4 - NW4; }
        else                     { src = (const float4_*)Wv; dst = wb + 2*DH*DIN; j = i - NX4 - 2*NW4; }
        float4_ v = src[j];
        short4_ o;
        o[0] = (short)f2bf(v[0]); o[1] = (short)f2bf(v[1]);
        o[2] = (short)f2bf(v[2]); o[3] = (short)f2bf(v[3]);
        ((short4_*)dst)[j] = o;
    }
}

// ---------------------------------------------------------------------------
// Kernel 1: QKV projection GEMM (128x128 tiles, LDS-staged, bf16 MFMA).
// mat==2 (V) epilogue transposes the 128x128 tile through LDS so the
// [b][dh][s] store is coalesced dwordx4 (R2 did scattered 2B stores).
// ---------------------------------------------------------------------------
__global__ __launch_bounds__(256) void qkv_gemm(
    const unsigned short* __restrict__ xb,
    const unsigned short* __restrict__ wb,
    const float* __restrict__ bq, const float* __restrict__ bk, const float* __restrict__ bv,
    unsigned short* __restrict__ qws, unsigned short* __restrict__ kws,
    unsigned short* __restrict__ vtws)
{
    __shared__ __align__(16) unsigned short smem[17408];  // 34.8 KB: Ab+Bb, reused as trans
    unsigned short* Ab = smem;          // [128][32]
    unsigned short* Bb = smem + 4096;   // [128][32]

    const int tm   = blockIdx.x;
    const int tc   = blockIdx.y;
    const int mat  = tc >> 2;
    const int nb   = (tc & 3) * 128;
    const int tid  = threadIdx.x;
    const int w    = tid >> 6;
    const int lane = tid & 63;
    const int l15  = lane & 15;
    const int quad = lane >> 4;
    const int wm   = (w & 1) * 64;
    const int wn   = (w >> 1) * 64;
    const int m0   = tm * 128;

    const unsigned short* wmat = wb + (size_t)mat * DH * DIN;

    float4_ zero = {0.f, 0.f, 0.f, 0.f};
    float4_ acc[4][4];
    #pragma unroll
    for (int i = 0; i < 4; i++)
        #pragma unroll
        for (int j = 0; j < 4; j++) acc[i][j] = zero;

    const int lr = lane >> 2;
    const int lb = (lane & 3) * 16;

    for (int kk = 0; kk < DIN; kk += 32) {
        #pragma unroll
        for (int c = 0; c < 2; c++) {
            int r = w * 32 + c * 16;
            const unsigned char* gA = (const unsigned char*)(xb + (size_t)(m0 + r) * DIN + kk);
            gload_lds16(gA + (size_t)lr * (DIN * 2) + lb, (void*)(Ab + r * 32));
            const unsigned char* gB = (const unsigned char*)(wmat + (size_t)(nb + r) * DIN + kk);
            gload_lds16(gB + (size_t)lr * (DIN * 2) + lb, (void*)(Bb + r * 32));
        }
        __syncthreads();
        short8 af[4], bf[4];
        #pragma unroll
        for (int mt = 0; mt < 4; mt++)
            af[mt] = *(const short8*)(Ab + (wm + mt * 16 + l15) * 32 + quad * 8);
        #pragma unroll
        for (int nt = 0; nt < 4; nt++)
            bf[nt] = *(const short8*)(Bb + (wn + nt * 16 + l15) * 32 + quad * 8);
        #pragma unroll
        for (int mt = 0; mt < 4; mt++)
            #pragma unroll
            for (int nt = 0; nt < 4; nt++)
                acc[mt][nt] = __builtin_amdgcn_mfma_f32_16x16x32_bf16(af[mt], bf[nt], acc[mt][nt], 0, 0, 0);
        __syncthreads();
    }

    if (mat < 2) {
        const float* bias  = (mat == 0) ? bq : bk;
        const float  scale = (mat == 0) ? 0.044194173824159216f : 1.0f;  // 1/sqrt(512) on Q
        unsigned short* dst = (mat == 0) ? qws : kws;
        #pragma unroll
        for (int nt = 0; nt < 4; nt++) {
            int n = nb + wn + nt * 16 + l15;
            float bv_ = bias[n];
            #pragma unroll
            for (int mt = 0; mt < 4; mt++) {
                #pragma unroll
                for (int r = 0; r < 4; r++) {
                    int m = m0 + wm + mt * 16 + quad * 4 + r;
                    dst[(size_t)m * DH + n] = f2bf((acc[mt][nt][r] + bv_) * scale);
                }
            }
        }
    } else {
        // V: transpose 128(s) x 128(dh) tile through LDS, coalesced store.
        unsigned short* trans = smem;   // [128 dh][136] shorts (stride-68dw: 2-way banks)
        #pragma unroll
        for (int nt = 0; nt < 4; nt++) {
            int dloc = wn + nt * 16 + l15;
            float bv_ = bv[nb + dloc];
            #pragma unroll
            for (int mt = 0; mt < 4; mt++) {
                short4_ pk;
                #pragma unroll
                for (int r = 0; r < 4; r++) pk[r] = (short)f2bf(acc[mt][nt][r] + bv_);
                *(short4_*)(trans + dloc * 136 + wm + mt * 16 + quad * 4) = pk;
            }
        }
        __syncthreads();
        int d  = tid >> 1;
        int ch = tid & 1;
        const short8* src = (const short8*)(trans + d * 136 + ch * 64);
        int bi = m0 >> 11;
        unsigned short* dst = vtws + (((size_t)(bi * DH + nb + d)) << 11) + (m0 & 2047) + ch * 64;
        #pragma unroll
        for (int j = 0; j < 8; j++) ((short8*)dst)[j] = src[j];
    }
}

// ---------------------------------------------------------------------------
// Kernel 2: flash attention. 256 blocks (1/CU), 4 waves, wave owns 16 q-rows.
// K AND V tiles double-buffered in LDS via async global_load_lds (134.6 KB);
// stage issued right after the single per-iter barrier so the vmcnt(0) drain
// at the NEXT barrier finds the load already complete. V chunk-swizzled
// (q^=(rr>>2)&3) and lds_p column-rotated for conflict-free b128 access.
// ---------------------------------------------------------------------------
__global__ __launch_bounds__(256, 1) void attn(
    const unsigned short* __restrict__ qws,
    const unsigned short* __restrict__ kws,
    const unsigned short* __restrict__ vtws,
    float* __restrict__ out)
{
    __shared__ unsigned char  kb[2][32 * 1040];     // 66.6 KB
    __shared__ unsigned char  vb[2][32 * 1024];     // 64 KB (swizzled chunks)
    __shared__ unsigned short lds_p[4][16][32];     // 4 KB per-wave P transpose

    const int bid  = blockIdx.x;
    const int b    = bid & 7;            // batch == XCD slot
    const int qt   = bid >> 3;
    const int tid  = threadIdx.x;
    const int w    = tid >> 6;
    const int lane = tid & 63;
    const int l15  = lane & 15;
    const int quad = lane >> 4;

    const int grow = b * S_ + qt * 64 + w * 16;

    const unsigned short* kbase = kws + ((size_t)b << 11) * DH;
    const unsigned short* vbase = vtws + (((size_t)b * DH) << 11);

    // staging lane-constants
    const int vd_sub = lane >> 2;                       // row within 16-row group
    const int vq     = (lane & 3) ^ ((lane >> 4) & 3);  // swizzled key-chunk

    // Q fragments resident: 64 VGPRs
    short8 qf[16];
    const short8* qp = (const short8*)(qws + (size_t)(grow + l15) * DH);
    #pragma unroll
    for (int ksi = 0; ksi < 16; ksi++) qf[ksi] = qp[ksi * 4 + quad];

    float4_ zero = {0.f, 0.f, 0.f, 0.f};
    float4_ o[32];
    #pragma unroll
    for (int i = 0; i < 32; i++) o[i] = zero;
    float m_[4], l_[4];
    #pragma unroll
    for (int r = 0; r < 4; r++) { m_[r] = -INFINITY; l_[r] = 0.f; }

    // prologue: stage tile 0 into buffer 0
    #pragma unroll
    for (int c = 0; c < 8; c++) {
        int row = w * 8 + c;
        gload_lds16((const unsigned char*)(kbase + (size_t)row * DH) + lane * 16,
                    kb[0] + row * 1040);
        int g = w * 8 + c;
        gload_lds16((const unsigned char*)(vbase + ((size_t)(g * 16 + vd_sub) << 11) + vq * 8),
                    vb[0] + g * 1024);
    }

    int cur = 0;
    for (int it = 0; it < 64; it++) {
        __syncthreads();   // buf[cur] staged (vmcnt drained); prev iter's reads done

        if (it + 1 < 64) { // stage next tile into other buffer: in flight during compute
            int ktn = (it + 1) * 32;
            #pragma unroll
            for (int c = 0; c < 8; c++) {
                int row = w * 8 + c;
                gload_lds16((const unsigned char*)(kbase + (size_t)(ktn + row) * DH) + lane * 16,
                            kb[1 - cur] + row * 1040);
                int g = w * 8 + c;
                gload_lds16((const unsigned char*)(vbase + ((size_t)(g * 16 + vd_sub) << 11) + ktn + vq * 8),
                            vb[1 - cur] + g * 1024);
            }
        }

        // ---- QK: 4 independent MFMA chains of depth 8 ----
        float4_ sA0 = zero, sA1 = zero, sB0 = zero, sB1 = zero;
        #pragma unroll
        for (int ksi = 0; ksi < 16; ksi += 2) {
            short8 k00 = *(const short8*)(kb[cur] + l15 * 1040 + ksi * 64 + quad * 16);
            short8 k01 = *(const short8*)(kb[cur] + (16 + l15) * 1040 + ksi * 64 + quad * 16);
            short8 k10 = *(const short8*)(kb[cur] + l15 * 1040 + (ksi + 1) * 64 + quad * 16);
            short8 k11 = *(const short8*)(kb[cur] + (16 + l15) * 1040 + (ksi + 1) * 64 + quad * 16);
            sA0 = __builtin_amdgcn_mfma_f32_16x16x32_bf16(qf[ksi],     k00, sA0, 0, 0, 0);
            sA1 = __builtin_amdgcn_mfma_f32_16x16x32_bf16(qf[ksi],     k01, sA1, 0, 0, 0);
            sB0 = __builtin_amdgcn_mfma_f32_16x16x32_bf16(qf[ksi + 1], k10, sB0, 0, 0, 0);
            sB1 = __builtin_amdgcn_mfma_f32_16x16x32_bf16(qf[ksi + 1], k11, sB1, 0, 0, 0);
        }
        float4_ sc0 = sA0 + sB0;
        float4_ sc1 = sA1 + sB1;

        // ---- online softmax ----
        float alpha[4], p0[4], p1[4];
        #pragma unroll
        for (int r = 0; r < 4; r++) {
            float v = fmaxf(sc0[r], sc1[r]);
            v = fmaxf(v, __shfl_xor(v, 1));
            v = fmaxf(v, __shfl_xor(v, 2));
            v = fmaxf(v, __shfl_xor(v, 4));
            v = fmaxf(v, __shfl_xor(v, 8));
            float mn = fmaxf(m_[r], v);
            alpha[r] = __expf(m_[r] - mn);
            m_[r] = mn;
            p0[r] = __expf(sc0[r] - mn);
            p1[r] = __expf(sc1[r] - mn);
            float s = p0[r] + p1[r];
            s += __shfl_xor(s, 1);
            s += __shfl_xor(s, 2);
            s += __shfl_xor(s, 4);
            s += __shfl_xor(s, 8);
            l_[r] = l_[r] * alpha[r] + s;
        }

        // ---- P: C-layout -> A-layout via swizzled per-wave LDS ----
        #pragma unroll
        for (int r = 0; r < 4; r++) {
            int off = ((quad * 2 + (r >> 1)) & 3) * 8;       // 8*((row>>1)&3)
            lds_p[w][quad * 4 + r][(l15 + off) & 31]      = f2bf(p0[r]);
            lds_p[w][quad * 4 + r][(l15 + 16 + off) & 31] = f2bf(p1[r]);
        }
        int rst = (quad * 8 + ((l15 >> 1) & 3) * 8) & 31;
        short8 pf = *(const short8*)&lds_p[w][l15][rst];

        // ---- rescale O when a new max appeared ----
        float amin = fminf(fminf(alpha[0], alpha[1]), fminf(alpha[2], alpha[3]));
        if (__any(amin < 1.0f)) {
            #pragma unroll
            for (int ct = 0; ct < 32; ct++) {
                #pragma unroll
                for (int r = 0; r < 4; r++) o[ct][r] *= alpha[r];
            }
        }

        // ---- O += P * V from swizzled LDS ----
        const unsigned char* vtile = vb[cur];
        const int vswz = (l15 * 4 + (quad ^ ((l15 >> 2) & 3))) * 16;
        #pragma unroll
        for (int ct = 0; ct < 32; ct++) {
            short8 vf = *(const short8*)(vtile + ct * 1024 + vswz);
            o[ct] = __builtin_amdgcn_mfma_f32_16x16x32_bf16(pf, vf, o[ct], 0, 0, 0);
        }
        cur ^= 1;
    }

    float rl[4];
    #pragma unroll
    for (int r = 0; r < 4; r++) rl[r] = 1.f / l_[r];
    #pragma unroll
    for (int ct = 0; ct < 32; ct++) {
        #pragma unroll
        for (int r = 0; r < 4; r++) {
            out[(size_t)(grow + quad * 4 + r) * DH + ct * 16 + l15] = o[ct][r] * rl[r];
        }
    }
}

extern "C" void kernel_launch(void* const* d_in, const int* in_sizes, int n_in,
                              void* d_out, int out_size, void* d_ws, size_t ws_size,
                              hipStream_t stream) {
    const float* x  = (const float*)d_in[0];
    const float* Wq = (const float*)d_in[1];
    const float* bq = (const float*)d_in[2];
    const float* Wk = (const float*)d_in[3];
    const float* bk = (const float*)d_in[4];
    const float* Wv = (const float*)d_in[5];
    const float* bv = (const float*)d_in[6];
    float* out = (float*)d_out;

    unsigned short* qws = (unsigned short*)d_ws;                 // [16384][512] bf16 (pre-scaled)
    unsigned short* kws = qws + (size_t)B_ * S_ * DH;            // [16384][512] bf16
    unsigned short* vt  = kws + (size_t)B_ * S_ * DH;            // [8][512][2048] bf16

    unsigned short* xb = (unsigned short*)d_out;                 // bf16 staging in d_out
    unsigned short* wb = xb + (size_t)B_ * S_ * DIN;

    conv_bf16<<<dim3(2048), dim3(256), 0, stream>>>(x, Wq, Wk, Wv, xb, wb);
    qkv_gemm<<<dim3(128, 12), dim3(256), 0, stream>>>(xb, wb, bq, bk, bv, qws, kws, vt);
    attn<<<dim3(256), dim3(256), 0, stream>>>(qws, kws, vt, out);
}